// Round 1
// baseline (728.500 us; speedup 1.0000x reference)
//
#include <hip/hip_runtime.h>
#include <math.h>

#define NB 32
#define NN 256
#define NF 8
#define NH 256
#define NITERS 3

__device__ __forceinline__ float sigmoidf_(float x){ return 1.0f/(1.0f+__expf(-x)); }

// K0: transpose jets-part of Wi -> WiJt[f][row] so k_embed reads coalesced
__global__ __launch_bounds__(256) void k_wijt(const float* __restrict__ Wi, float* __restrict__ WiJt){
  for (int e = threadIdx.x; e < NF*768; e += 256){
    int f = e / 768, row = e % 768;
    WiJt[e] = Wi[(size_t)row*264 + 256 + f];
  }
}

// K1: h = tanh(jets@W_emb + b_emb); gjets = jets@Wi[:,256:].T + bi  (iteration-invariant)
__global__ __launch_bounds__(256) void k_embed(const float* __restrict__ jets,
    const float* __restrict__ W_emb, const float* __restrict__ b_emb,
    const float* __restrict__ bi, const float* __restrict__ WiJt,
    float* __restrict__ h, float* __restrict__ gjets){
  int bn = blockIdx.x, t = threadIdx.x;
  __shared__ float jr[NF];
  if (t < NF) jr[t] = jets[bn*NF + t];
  __syncthreads();
  float a = b_emb[t];
  #pragma unroll
  for (int f=0; f<NF; ++f) a = fmaf(jr[f], W_emb[f*NH + t], a);
  h[(size_t)bn*NH + t] = tanhf(a);
  #pragma unroll
  for (int g=0; g<3; ++g){
    int row = g*NH + t;
    float acc = bi[row];
    #pragma unroll
    for (int f=0; f<NF; ++f) acc = fmaf(jr[f], WiJt[f*768 + row], acc);
    gjets[(size_t)bn*768 + row] = acc;
  }
}

// K2 (per iter): softmax weights a[j] (s_i cancels!), hbar = a@h, msgvec = tanh(hbar@W_msg+b_msg),
// gmsg[b,:] = msgvec @ Wi[:, :256].T   (one block per batch)
__global__ __launch_bounds__(256) void k_attn(const float* h,
    const float* __restrict__ w_edge, const float* __restrict__ W_msg,
    const float* __restrict__ b_msg, const float* __restrict__ Wi,
    float* __restrict__ gmsg){
  int b = blockIdx.x, t = threadIdx.x;
  __shared__ float we[NH];
  __shared__ float aw[NN];
  __shared__ float red[256];
  __shared__ float hbar[NH];
  __shared__ float mv[NH];
  const float* hb = h + (size_t)b*NN*NH;
  we[t] = w_edge[t];
  __syncthreads();
  float s = 0.f;
  for (int k=0;k<NH;++k) s = fmaf(hb[(size_t)t*NH+k], we[k], s);
  red[t] = s;
  __syncthreads();
  for (int o=128;o>0;o>>=1){ if (t<o) red[t]=fmaxf(red[t],red[t+o]); __syncthreads(); }
  float mx = red[0];
  __syncthreads();
  float e = __expf(s-mx);
  red[t] = e;
  __syncthreads();
  for (int o=128;o>0;o>>=1){ if (t<o) red[t]+=red[t+o]; __syncthreads(); }
  float aval = e/red[0];
  aw[t] = aval;
  __syncthreads();
  float hbv = 0.f;
  for (int j=0;j<NN;++j) hbv = fmaf(aw[j], hb[(size_t)j*NH+t], hbv);
  hbar[t]=hbv;
  __syncthreads();
  float m = b_msg[t];
  for (int k=0;k<NH;++k) m = fmaf(hbar[k], W_msg[k*NH+t], m);
  mv[t] = tanhf(m);
  __syncthreads();
  #pragma unroll
  for (int g=0; g<3; ++g){
    int row = g*NH+t;
    const float* wrow = Wi + (size_t)row*264;
    float acc=0.f;
    for (int k=0;k<NH;++k) acc = fmaf(mv[k], wrow[k], acc);
    gmsg[b*768+row] = acc;
  }
}

// K3 (per iter): fused gh = h@Wh.T + bh  and GRU update, in place on h.
// BM=32 rows/block, col-chunks of 64 over 768, K tiled by 64. Thread tile: 4 rows x 2 cols x 3 gates.
__global__ __launch_bounds__(256) void k_gru(const float* hg,
    const float* __restrict__ Wh, const float* __restrict__ bh,
    const float* __restrict__ gjets, const float* __restrict__ gmsg,
    float* hout){
  __shared__ float Ah[32][260];   // +4 pad: bank = (4*row+k)%32, broadcast rows -> conflict-free
  __shared__ float Bs[64][66];    // +2 pad: bank = (2*c+k)%32, c distinct mod 32 -> 2-way (free)
  __shared__ float gm[768];
  int t = threadIdx.x;
  int row0 = blockIdx.x * 32;
  int b = row0 >> 8;
  for (int i=0;i<32;++i) Ah[i][t] = hg[(size_t)(row0+i)*NH + t];
  gm[t] = gmsg[b*768+t]; gm[256+t]=gmsg[b*768+256+t]; gm[512+t]=gmsg[b*768+512+t];
  int tr = t >> 5, tc = t & 31;
  __syncthreads();
  for (int hcb=0; hcb<4; ++hcb){
    float acc[3][4][2];
    #pragma unroll
    for (int g=0;g<3;++g)
      #pragma unroll
      for (int i=0;i<4;++i){ acc[g][i][0]=0.f; acc[g][i][1]=0.f; }
    for (int g=0; g<3; ++g){
      int colbase = g*NH + hcb*64;
      for (int kt=0; kt<4; ++kt){
        __syncthreads();
        // stage Bs[c][k] = Wh[(colbase+c)*256 + kt*64 + k]
        #pragma unroll
        for (int p=0;p<4;++p){
          int e = p*1024 + t*4;
          int c = e >> 6, k = e & 63;
          const float4 v = *reinterpret_cast<const float4*>(&Wh[(size_t)(colbase+c)*NH + kt*64 + k]);
          Bs[c][k] = v.x; Bs[c][k+1] = v.y; Bs[c][k+2] = v.z; Bs[c][k+3] = v.w;
        }
        __syncthreads();
        #pragma unroll
        for (int k=0;k<64;k+=2){
          float2 av[4], bv[2];
          #pragma unroll
          for (int i=0;i<4;++i) av[i] = *reinterpret_cast<const float2*>(&Ah[tr+8*i][kt*64+k]);
          #pragma unroll
          for (int j=0;j<2;++j) bv[j] = *reinterpret_cast<const float2*>(&Bs[tc+32*j][k]);
          #pragma unroll
          for (int i=0;i<4;++i)
            #pragma unroll
            for (int j=0;j<2;++j){
              acc[g][i][j] = fmaf(av[i].x, bv[j].x, acc[g][i][j]);
              acc[g][i][j] = fmaf(av[i].y, bv[j].y, acc[g][i][j]);
            }
        }
      }
    }
    // GRU epilogue for this 64-col block, straight from registers
    #pragma unroll
    for (int i=0;i<4;++i){
      int row = tr + 8*i;
      size_t gr = (size_t)(row0 + row);
      #pragma unroll
      for (int j=0;j<2;++j){
        int c = tc + 32*j;
        int hcol = hcb*64 + c;
        float gir = gm[hcol]      + gjets[gr*768 + hcol];
        float giz = gm[NH+hcol]   + gjets[gr*768 + NH + hcol];
        float gin = gm[2*NH+hcol] + gjets[gr*768 + 2*NH + hcol];
        float ghr = acc[0][i][j] + bh[hcol];
        float ghz = acc[1][i][j] + bh[NH+hcol];
        float ghn = acc[2][i][j] + bh[2*NH+hcol];
        float r = sigmoidf_(gir + ghr);
        float z = sigmoidf_(giz + ghz);
        float n = tanhf(gin + r*ghn);
        float ho = Ah[row][hcol];
        hout[gr*NH + hcol] = (1.f - z)*n + z*ho;
      }
    }
  }
}

// K4: y = relu(h@Wr1+br1), per-block column partial sums over its 32 rows -> atomicAdd zsum[b,:]
__global__ __launch_bounds__(256) void k_readout(const float* hg,
    const float* __restrict__ Wr1, const float* __restrict__ br1,
    float* __restrict__ zsum){
  __shared__ float Ah[32][260];
  __shared__ float Bs[64][66];
  __shared__ float yb[32][68];
  int t = threadIdx.x;
  int row0 = blockIdx.x * 32;
  int b = row0 >> 8;
  for (int i=0;i<32;++i) Ah[i][t] = hg[(size_t)(row0+i)*NH + t];
  int tr = t >> 5, tc = t & 31;
  __syncthreads();
  for (int hcb=0; hcb<4; ++hcb){
    int colbase = hcb*64;
    float acc[4][2];
    #pragma unroll
    for (int i=0;i<4;++i){ acc[i][0]=0.f; acc[i][1]=0.f; }
    for (int kt=0; kt<4; ++kt){
      __syncthreads();
      // stage Bs[c][k] = Wr1[(kt*64+k)*256 + colbase + c]  (non-transposed B)
      #pragma unroll
      for (int p=0;p<4;++p){
        int e = p*1024 + t*4;
        int c = e & 63, k = e >> 6;
        const float4 v = *reinterpret_cast<const float4*>(&Wr1[(size_t)(kt*64+k)*NH + colbase + c]);
        Bs[c][k] = v.x; Bs[c+1][k] = v.y; Bs[c+2][k] = v.z; Bs[c+3][k] = v.w;
      }
      __syncthreads();
      #pragma unroll
      for (int k=0;k<64;k+=2){
        float2 av[4], bv[2];
        #pragma unroll
        for (int i=0;i<4;++i) av[i] = *reinterpret_cast<const float2*>(&Ah[tr+8*i][kt*64+k]);
        #pragma unroll
        for (int j=0;j<2;++j) bv[j] = *reinterpret_cast<const float2*>(&Bs[tc+32*j][k]);
        #pragma unroll
        for (int i=0;i<4;++i)
          #pragma unroll
          for (int j=0;j<2;++j){
            acc[i][j] = fmaf(av[i].x, bv[j].x, acc[i][j]);
            acc[i][j] = fmaf(av[i].y, bv[j].y, acc[i][j]);
          }
      }
    }
    #pragma unroll
    for (int i=0;i<4;++i)
      #pragma unroll
      for (int j=0;j<2;++j)
        yb[tr+8*i][tc+32*j] = fmaxf(acc[i][j] + br1[colbase + tc+32*j], 0.f);
    __syncthreads();
    if (t < 64){
      float cs = 0.f;
      #pragma unroll
      for (int r=0;r<32;++r) cs += yb[r][t];
      atomicAdd(&zsum[b*NH + colbase + t], cs);
    }
    __syncthreads();
  }
}

// K5: out[b,:] = zsum[b,:] @ Wr2 + N*br2
__global__ __launch_bounds__(256) void k_final(const float* __restrict__ zsum,
    const float* __restrict__ Wr2, const float* __restrict__ br2,
    float* __restrict__ out){
  int b = blockIdx.x, t = threadIdx.x;
  __shared__ float zs[NH];
  zs[t] = zsum[b*NH + t];
  __syncthreads();
  float acc = 0.f;
  for (int k=0;k<NH;++k) acc = fmaf(zs[k], Wr2[k*NH + t], acc);
  out[b*NH + t] = acc + 256.0f*br2[t];
}

extern "C" void kernel_launch(void* const* d_in, const int* in_sizes, int n_in,
                              void* d_out, int out_size, void* d_ws, size_t ws_size,
                              hipStream_t stream){
  (void)in_sizes; (void)n_in; (void)out_size; (void)ws_size;
  const float* jets  = (const float*)d_in[0];
  const float* W_emb = (const float*)d_in[1];
  const float* b_emb = (const float*)d_in[2];
  const float* w_edge= (const float*)d_in[3];
  // d_in[4] = b_edge: cancels in softmax, unused
  const float* W_msg = (const float*)d_in[5];
  const float* b_msg = (const float*)d_in[6];
  const float* Wi    = (const float*)d_in[7];
  const float* bi    = (const float*)d_in[8];
  const float* Wh    = (const float*)d_in[9];
  const float* bh    = (const float*)d_in[10];
  const float* Wr1   = (const float*)d_in[11];
  const float* br1   = (const float*)d_in[12];
  const float* Wr2   = (const float*)d_in[13];
  const float* br2   = (const float*)d_in[14];
  float* out = (float*)d_out;
  float* ws = (float*)d_ws;
  float* h     = ws;                 // 8192*256  = 2,097,152 f
  float* gjets = ws + 2097152;       // 8192*768  = 6,291,456 f
  float* gmsg  = ws + 8388608;       // 32*768
  float* zsum  = ws + 8413184;       // 32*256
  float* WiJt  = ws + 8421376;       // 8*768
  hipMemsetAsync(zsum, 0, NB*NH*sizeof(float), stream);
  k_wijt<<<1,256,0,stream>>>(Wi, WiJt);
  k_embed<<<NB*NN,256,0,stream>>>(jets, W_emb, b_emb, bi, WiJt, h, gjets);
  for (int it=0; it<NITERS; ++it){
    k_attn<<<NB,256,0,stream>>>(h, w_edge, W_msg, b_msg, Wi, gmsg);
    k_gru<<<NB*NN/32,256,0,stream>>>(h, Wh, bh, gjets, gmsg, h);
  }
  k_readout<<<NB*NN/32,256,0,stream>>>(h, Wr1, br1, zsum);
  k_final<<<NB,256,0,stream>>>(zsum, Wr2, br2, out);
}

// Round 3
// 247.532 us; speedup vs baseline: 2.9431x; 2.9431x over previous
//
#include <hip/hip_runtime.h>
#include <math.h>

#define NB 32
#define NN 256
#define NF 8
#define NH 256
#define NITERS 3

typedef __attribute__((ext_vector_type(8))) short short8;
typedef __attribute__((ext_vector_type(4))) float f32x4;
typedef unsigned short ushort_t;

__device__ __forceinline__ float sigmoidf_(float x){ return 1.0f/(1.0f+__expf(-x)); }
__device__ __forceinline__ ushort_t f2bf(float x){
  unsigned int u = __float_as_uint(x);
  u = u + 0x7fff + ((u>>16)&1);
  return (ushort_t)(u>>16);
}
__device__ __forceinline__ float bf2f(ushort_t b){
  return __uint_as_float(((unsigned int)b)<<16);
}

// ---- prep: weight transposes / bf16 conversions (once per call) ----
__global__ __launch_bounds__(256) void k_prep(const float* __restrict__ Wi,
    const float* __restrict__ Wh, const float* __restrict__ Wr1,
    float* __restrict__ WiJt, float* __restrict__ WiMt,
    ushort_t* __restrict__ WhB, ushort_t* __restrict__ Wr1T){
  int gid = blockIdx.x*256 + threadIdx.x;
  int np = gridDim.x*256;
  for (int e=gid; e<NF*768; e+=np){ int f=e/768, row=e%768; WiJt[e]=Wi[(size_t)row*264 + 256 + f]; }
  for (int e=gid; e<256*768; e+=np){ int k=e/768, row=e%768; WiMt[e]=Wi[(size_t)row*264 + k]; }
  for (int e=gid; e<768*256; e+=np){ WhB[e]=f2bf(Wh[e]); }
  for (int e=gid; e<256*256; e+=np){ int n=e>>8, k=e&255; Wr1T[e]=f2bf(Wr1[(size_t)k*256+n]); }
}

// ---- embed: h = tanh(jets@W_emb+b_emb) (f32+bf16); gjets = jets@WiJ.T+bi (bf16) ----
__global__ __launch_bounds__(256) void k_embed(const float* __restrict__ jets,
    const float* __restrict__ W_emb, const float* __restrict__ b_emb,
    const float* __restrict__ bi, const float* __restrict__ WiJt,
    float* __restrict__ h32, ushort_t* __restrict__ hbf, ushort_t* __restrict__ gjets){
  int bn = blockIdx.x, t = threadIdx.x;
  __shared__ float jr[NF];
  if (t < NF) jr[t] = jets[bn*NF + t];
  __syncthreads();
  float a = b_emb[t];
  #pragma unroll
  for (int f=0; f<NF; ++f) a = fmaf(jr[f], W_emb[f*NH + t], a);
  float hv = tanhf(a);
  h32[(size_t)bn*NH + t] = hv;
  hbf[(size_t)bn*NH + t] = f2bf(hv);
  #pragma unroll
  for (int g=0; g<3; ++g){
    int row = g*NH + t;
    float acc = bi[row];
    #pragma unroll
    for (int f=0; f<NF; ++f) acc = fmaf(jr[f], WiJt[f*768 + row], acc);
    gjets[(size_t)bn*768 + row] = f2bf(acc);
  }
}

// ---- edge scores: s_all[m] = h[m,:]·w_edge ----
__global__ __launch_bounds__(256) void k_edge_s(const float* __restrict__ h,
    const float* __restrict__ we, float* __restrict__ s_all){
  int t = threadIdx.x;
  int row = blockIdx.x*64 + (t>>2);
  int p = t&3;
  const float4* hp = (const float4*)(h + (size_t)row*NH);
  const float4* wp = (const float4*)we;
  float s = 0.f;
  #pragma unroll
  for (int j=0;j<16;++j){
    float4 v = hp[p + j*4];
    float4 w = wp[p + j*4];
    s = fmaf(v.x,w.x,fmaf(v.y,w.y,fmaf(v.z,w.z,fmaf(v.w,w.w,s))));
  }
  s += __shfl_xor(s,1);
  s += __shfl_xor(s,2);
  if (p==0) s_all[row] = s;
}

// ---- attn tail: softmax -> hbar -> msg -> gmsg (32 blocks) ----
__global__ __launch_bounds__(256) void k_attn2(const float* __restrict__ h,
    const float* __restrict__ s_all, const float* __restrict__ W_msg,
    const float* __restrict__ b_msg, const float* __restrict__ WiMt,
    float* __restrict__ gmsg){
  int b = blockIdx.x, t = threadIdx.x;
  __shared__ float red[256], aw[256], hbar[256], mv[256];
  const float* hb = h + (size_t)b*NN*NH;
  float s = s_all[b*NN + t];
  red[t] = s; __syncthreads();
  for (int o=128;o>0;o>>=1){ if (t<o) red[t]=fmaxf(red[t],red[t+o]); __syncthreads(); }
  float mx = red[0]; __syncthreads();
  float e = __expf(s-mx); red[t]=e; __syncthreads();
  for (int o=128;o>0;o>>=1){ if (t<o) red[t]+=red[t+o]; __syncthreads(); }
  aw[t] = e/red[0]; __syncthreads();
  float hbv = 0.f;
  for (int j=0;j<NN;++j) hbv = fmaf(aw[j], hb[(size_t)j*NH+t], hbv);
  hbar[t]=hbv; __syncthreads();
  float m = b_msg[t];
  for (int k=0;k<NH;++k) m = fmaf(hbar[k], W_msg[k*NH+t], m);
  mv[t] = tanhf(m); __syncthreads();
  #pragma unroll
  for (int g=0; g<3; ++g){
    int rowi = g*NH+t;
    float a2 = 0.f;
    for (int k=0;k<NH;++k) a2 = fmaf(mv[k], WiMt[k*768 + rowi], a2);
    gmsg[b*768+rowi] = a2;
  }
}

// ---- GRU via MFMA: gh = h@Wh.T (bf16 MFMA), fused GRU epilogue ----
// grid: (M/64) x 4 hcol-strips = 512 blocks. 4 waves as 2x2: wave = 32 rows x 32 cols per gate.
__global__ __launch_bounds__(256) void k_gru_mfma(
    const ushort_t* __restrict__ hbf, const float* __restrict__ hf32,
    const ushort_t* __restrict__ WhB, const float* __restrict__ bh,
    const ushort_t* __restrict__ gjets, const float* __restrict__ gmsg,
    float* __restrict__ h32_out, ushort_t* __restrict__ hbf_out)
{
  __shared__ __align__(16) short As[64*32];
  __shared__ __align__(16) short Bs[3*64*32];
  __shared__ float gm_s[192], bh_s[192];
  int t = threadIdx.x;
  int hcb = blockIdx.x & 3, mblk = blockIdx.x >> 2;
  int m0 = mblk*64, hc0 = hcb*64, b = m0 >> 8;
  if (t < 192){
    int g = t>>6, c = t&63;
    gm_s[t] = gmsg[b*768 + g*256 + hc0 + c];
    bh_s[t] = bh[g*256 + hc0 + c];
  }
  int lane = t & 63, w = t >> 6;
  int wr = w >> 1, wc = w & 1;
  int q = lane >> 4, r = lane & 15;
  int srow = t >> 2, sseg = t & 3;
  f32x4 acc[3][2][2] = {};
  for (int kt = 0; kt < 8; ++kt){
    __syncthreads();
    *(uint4*)&As[t*8] = *(const uint4*)&hbf[(size_t)(m0+srow)*256 + kt*32 + sseg*8];
    #pragma unroll
    for (int g = 0; g < 3; ++g)
      *(uint4*)&Bs[g*2048 + t*8] = *(const uint4*)&WhB[(size_t)(g*256 + hc0 + srow)*256 + kt*32 + sseg*8];
    __syncthreads();
    short8 af[2], bfr[3][2];
    #pragma unroll
    for (int fm=0; fm<2; ++fm)
      af[fm] = *(const short8*)&As[(wr*32 + fm*16 + r)*32 + q*8];
    #pragma unroll
    for (int g=0; g<3; ++g)
      #pragma unroll
      for (int fn=0; fn<2; ++fn)
        bfr[g][fn] = *(const short8*)&Bs[g*2048 + (wc*32 + fn*16 + r)*32 + q*8];
    #pragma unroll
    for (int g=0; g<3; ++g)
      #pragma unroll
      for (int fm=0; fm<2; ++fm)
        #pragma unroll
        for (int fn=0; fn<2; ++fn)
          acc[g][fm][fn] = __builtin_amdgcn_mfma_f32_16x16x32_bf16(af[fm], bfr[g][fn], acc[g][fm][fn], 0,0,0);
  }
  #pragma unroll
  for (int fm=0; fm<2; ++fm)
    #pragma unroll
    for (int fn=0; fn<2; ++fn){
      int cloc = wc*32 + fn*16 + r;
      int hcol = hc0 + cloc;
      #pragma unroll
      for (int jj=0; jj<4; ++jj){
        int m = m0 + wr*32 + fm*16 + q*4 + jj;
        float gir = bf2f(gjets[(size_t)m*768 + hcol])       + gm_s[cloc];
        float giz = bf2f(gjets[(size_t)m*768 + 256 + hcol]) + gm_s[64+cloc];
        float gin = bf2f(gjets[(size_t)m*768 + 512 + hcol]) + gm_s[128+cloc];
        float rr = sigmoidf_(gir + acc[0][fm][fn][jj] + bh_s[cloc]);
        float zz = sigmoidf_(giz + acc[1][fm][fn][jj] + bh_s[64+cloc]);
        float nn = tanhf(gin + rr*(acc[2][fm][fn][jj] + bh_s[128+cloc]));
        float ho = hf32[(size_t)m*256 + hcol];
        float hn = (1.f - zz)*nn + zz*ho;
        h32_out[(size_t)m*256 + hcol] = hn;
        hbf_out[(size_t)m*256 + hcol] = f2bf(hn);
      }
    }
}

// ---- readout via MFMA: y = relu(h@Wr1+br1), column-sum per batch -> zsum ----
__global__ __launch_bounds__(256) void k_readout_mfma(
    const ushort_t* __restrict__ hbf, const ushort_t* __restrict__ Wr1T,
    const float* __restrict__ br1, float* __restrict__ zsum)
{
  __shared__ __align__(16) short As[64*32];
  __shared__ __align__(16) short Bs[64*32];
  int t = threadIdx.x;
  int ncb = blockIdx.x & 3, mblk = blockIdx.x >> 2;
  int m0 = mblk*64, nc0 = ncb*64, b = m0 >> 8;
  int lane = t & 63, w = t >> 6;
  int wr = w >> 1, wc = w & 1;
  int q = lane >> 4, r = lane & 15;
  int srow = t >> 2, sseg = t & 3;
  f32x4 acc[2][2] = {};
  for (int kt = 0; kt < 8; ++kt){
    __syncthreads();
    *(uint4*)&As[t*8] = *(const uint4*)&hbf[(size_t)(m0+srow)*256 + kt*32 + sseg*8];
    *(uint4*)&Bs[t*8] = *(const uint4*)&Wr1T[(size_t)(nc0+srow)*256 + kt*32 + sseg*8];
    __syncthreads();
    short8 af[2], bfr[2];
    #pragma unroll
    for (int fm=0; fm<2; ++fm)
      af[fm] = *(const short8*)&As[(wr*32 + fm*16 + r)*32 + q*8];
    #pragma unroll
    for (int fn=0; fn<2; ++fn)
      bfr[fn] = *(const short8*)&Bs[(wc*32 + fn*16 + r)*32 + q*8];
    #pragma unroll
    for (int fm=0; fm<2; ++fm)
      #pragma unroll
      for (int fn=0; fn<2; ++fn)
        acc[fm][fn] = __builtin_amdgcn_mfma_f32_16x16x32_bf16(af[fm], bfr[fn], acc[fm][fn], 0,0,0);
  }
  #pragma unroll
  for (int fn=0; fn<2; ++fn){
    int n = nc0 + wc*32 + fn*16 + r;
    float bb = br1[n];
    float cs = 0.f;
    #pragma unroll
    for (int fm=0; fm<2; ++fm)
      #pragma unroll
      for (int jj=0; jj<4; ++jj)
        cs += fmaxf(acc[fm][fn][jj] + bb, 0.f);
    cs += __shfl_xor(cs, 16);
    cs += __shfl_xor(cs, 32);
    if (q == 0) atomicAdd(&zsum[b*256 + n], cs);
  }
}

// ---- final: out[b,:] = zsum[b,:]@Wr2 + N*br2 ----
__global__ __launch_bounds__(256) void k_final(const float* __restrict__ zsum,
    const float* __restrict__ Wr2, const float* __restrict__ br2,
    float* __restrict__ out){
  int b = blockIdx.x, t = threadIdx.x;
  __shared__ float zs[NH];
  zs[t] = zsum[b*NH + t];
  __syncthreads();
  float acc = 0.f;
  for (int k=0;k<NH;++k) acc = fmaf(zs[k], Wr2[k*NH + t], acc);
  out[b*NH + t] = acc + 256.0f*br2[t];
}

extern "C" void kernel_launch(void* const* d_in, const int* in_sizes, int n_in,
                              void* d_out, int out_size, void* d_ws, size_t ws_size,
                              hipStream_t stream){
  (void)in_sizes; (void)n_in; (void)out_size; (void)ws_size;
  const float* jets  = (const float*)d_in[0];
  const float* W_emb = (const float*)d_in[1];
  const float* b_emb = (const float*)d_in[2];
  const float* w_edge= (const float*)d_in[3];
  // d_in[4] = b_edge: cancels in softmax
  const float* W_msg = (const float*)d_in[5];
  const float* b_msg = (const float*)d_in[6];
  const float* Wi    = (const float*)d_in[7];
  const float* bi    = (const float*)d_in[8];
  const float* Wh    = (const float*)d_in[9];
  const float* bh    = (const float*)d_in[10];
  const float* Wr1   = (const float*)d_in[11];
  const float* br1   = (const float*)d_in[12];
  const float* Wr2   = (const float*)d_in[13];
  const float* br2   = (const float*)d_in[14];
  float* out = (float*)d_out;
  float* ws = (float*)d_ws;
  // workspace layout (float-slot units) -- hbf buffers are 8192*256 bf16 = 1,048,576 float-slots EACH
  float* h32      = ws;                             // 2,097,152
  ushort_t* hbf_0 = (ushort_t*)(ws + 2097152);      // 1,048,576 f
  ushort_t* hbf_1 = (ushort_t*)(ws + 3145728);      // 1,048,576 f
  ushort_t* gjets = (ushort_t*)(ws + 4194304);      // 3,145,728 f
  float* gmsg  = ws + 7340032;                      // 24,576
  float* zsum  = ws + 7364608;                      // 8,192
  float* WiJt  = ws + 7372800;                      // 6,144
  float* WiMt  = ws + 7378944;                      // 196,608
  ushort_t* WhB  = (ushort_t*)(ws + 7575552);       // 98,304 f
  ushort_t* Wr1T = (ushort_t*)(ws + 7673856);       // 32,768 f
  float* s_all = ws + 7706624;                      // 8,192  (end: 7,714,816 f = 30.9 MB)
  ushort_t* hbf[2] = {hbf_0, hbf_1};

  hipMemsetAsync(zsum, 0, NB*NH*sizeof(float), stream);
  k_prep<<<256,256,0,stream>>>(Wi, Wh, Wr1, WiJt, WiMt, WhB, Wr1T);
  k_embed<<<NB*NN,256,0,stream>>>(jets, W_emb, b_emb, bi, WiJt, h32, hbf[0], gjets);
  for (int it=0; it<NITERS; ++it){
    int cur = it & 1, nxt = cur ^ 1;
    k_edge_s<<<NB*NN/64,256,0,stream>>>(h32, w_edge, s_all);
    k_attn2<<<NB,256,0,stream>>>(h32, s_all, W_msg, b_msg, WiMt, gmsg);
    k_gru_mfma<<<512,256,0,stream>>>(hbf[cur], h32, WhB, bh, gjets, gmsg,
                                     h32, hbf[nxt]);
  }
  k_readout_mfma<<<512,256,0,stream>>>(hbf[NITERS&1], Wr1T, br1, zsum);
  k_final<<<NB,256,0,stream>>>(zsum, Wr2, br2, out);
}

// Round 4
// 153.723 us; speedup vs baseline: 4.7390x; 1.6102x over previous
//
#include <hip/hip_runtime.h>
#include <math.h>

#define NB 32
#define NN 256
#define NF 8
#define NH 256
#define NITERS 3

typedef __attribute__((ext_vector_type(8))) short short8;
typedef __attribute__((ext_vector_type(4))) float f32x4;
typedef unsigned short ushort_t;

__device__ __forceinline__ float sigmoidf_(float x){ return 1.0f/(1.0f+__expf(-x)); }
__device__ __forceinline__ ushort_t f2bf(float x){
  unsigned int u = __float_as_uint(x);
  u = u + 0x7fff + ((u>>16)&1);
  return (ushort_t)(u>>16);
}
__device__ __forceinline__ float bf2f(ushort_t b){
  return __uint_as_float(((unsigned int)b)<<16);
}

// ---- prep: weight transposes / bf16 conversions (once per call) ----
__global__ __launch_bounds__(256) void k_prep(const float* __restrict__ Wi,
    const float* __restrict__ Wh, const float* __restrict__ Wr1,
    float* __restrict__ WiJt, float* __restrict__ WiMt,
    ushort_t* __restrict__ WhB, ushort_t* __restrict__ Wr1T){
  int gid = blockIdx.x*256 + threadIdx.x;
  int np = gridDim.x*256;
  for (int e=gid; e<NF*768; e+=np){ int f=e/768, row=e%768; WiJt[e]=Wi[(size_t)row*264 + 256 + f]; }
  for (int e=gid; e<256*768; e+=np){ int k=e/768, row=e%768; WiMt[e]=Wi[(size_t)row*264 + k]; }
  for (int e=gid; e<768*256; e+=np){ WhB[e]=f2bf(Wh[e]); }
  for (int e=gid; e<256*256; e+=np){ int n=e>>8, k=e&255; Wr1T[e]=f2bf(Wr1[(size_t)k*256+n]); }
}

// ---- embed: h = tanh(jets@W_emb+b_emb) -> hbf (bf16); gjets; s0[row] = h·w_edge ----
__global__ __launch_bounds__(256) void k_embed(const float* __restrict__ jets,
    const float* __restrict__ W_emb, const float* __restrict__ b_emb,
    const float* __restrict__ bi, const float* __restrict__ WiJt,
    const float* __restrict__ w_edge,
    ushort_t* __restrict__ hbf, ushort_t* __restrict__ gjets, float* __restrict__ s0){
  int bn = blockIdx.x, t = threadIdx.x;
  __shared__ float jr[NF];
  __shared__ float red[256];
  if (t < NF) jr[t] = jets[bn*NF + t];
  __syncthreads();
  float a = b_emb[t];
  #pragma unroll
  for (int f=0; f<NF; ++f) a = fmaf(jr[f], W_emb[f*NH + t], a);
  float hv = tanhf(a);
  hbf[(size_t)bn*NH + t] = f2bf(hv);
  red[t] = hv * w_edge[t];
  __syncthreads();
  for (int o=128;o>0;o>>=1){ if (t<o) red[t]+=red[t+o]; __syncthreads(); }
  if (t==0) s0[bn] = red[0];
  #pragma unroll
  for (int g=0; g<3; ++g){
    int row = g*NH + t;
    float acc = bi[row];
    #pragma unroll
    for (int f=0; f<NF; ++f) acc = fmaf(jr[f], WiJt[f*768 + row], acc);
    gjets[(size_t)bn*768 + row] = f2bf(acc);
  }
}

// ---- attn 1: per (batch, j-chunk) partial of hbar = softmax(s) @ h ; 256 blocks ----
__global__ __launch_bounds__(256) void k_attn_hbar(const ushort_t* __restrict__ hbf,
    const float* __restrict__ s_buf, float* __restrict__ hbar){
  int t = threadIdx.x;
  int b = blockIdx.x >> 3, jc = (blockIdx.x & 7) << 5;
  __shared__ float eS[256], red[256];
  float s = s_buf[b*NN + t];
  red[t] = s; __syncthreads();
  for (int o=128;o>0;o>>=1){ if (t<o) red[t]=fmaxf(red[t],red[t+o]); __syncthreads(); }
  float mx = red[0]; __syncthreads();
  float e = __expf(s-mx); eS[t]=e; red[t]=e; __syncthreads();
  for (int o=128;o>0;o>>=1){ if (t<o) red[t]+=red[t+o]; __syncthreads(); }
  float rZ = 1.0f/red[0];
  const ushort_t* hb = hbf + (size_t)b*NN*NH;
  float p = 0.f;
  #pragma unroll
  for (int j=0;j<32;++j)
    p = fmaf(eS[jc+j], bf2f(hb[(size_t)(jc+j)*NH + t]), p);
  atomicAdd(&hbar[b*NH+t], p*rZ);
}

// ---- attn 2: mv = tanh(hbar@W_msg+b_msg); 16 blocks x 16 cols (all 32 batches) ----
__global__ __launch_bounds__(256) void k_msg(const float* __restrict__ hbar,
    const float* __restrict__ W_msg, const float* __restrict__ b_msg,
    float* __restrict__ mv){
  int t = threadIdx.x;
  int c0 = blockIdx.x * 16;
  __shared__ float hS[32][257];
  __shared__ float wS[256][16];
  #pragma unroll
  for (int i=0;i<32;++i) hS[i][t] = hbar[i*NH + t];
  #pragma unroll
  for (int i=0;i<16;++i){
    int k = i*16 + (t>>4);
    wS[k][t&15] = W_msg[k*NH + c0 + (t&15)];
  }
  __syncthreads();
  int b = t >> 3, cl = t & 7;
  float a0=0.f, a1=0.f;
  for (int k=0;k<256;++k){
    float hv = hS[b][k];
    a0 = fmaf(hv, wS[k][cl],   a0);
    a1 = fmaf(hv, wS[k][cl+8], a1);
  }
  mv[b*NH + c0 + cl]     = tanhf(a0 + b_msg[c0+cl]);
  mv[b*NH + c0 + cl + 8] = tanhf(a1 + b_msg[c0+cl+8]);
}

// ---- attn 3: gmsg = mv @ WiM^T ; 24 blocks x 32 rows (all 32 batches) ----
__global__ __launch_bounds__(256) void k_gmsg(const float* __restrict__ mv,
    const float* __restrict__ WiMt, float* __restrict__ gmsg){
  int t = threadIdx.x;
  int r0 = blockIdx.x * 32;
  __shared__ float mS[32][257];
  __shared__ float wS[256][32];
  #pragma unroll
  for (int i=0;i<32;++i) mS[i][t] = mv[i*NH + t];
  #pragma unroll
  for (int i=0;i<32;++i){
    int k = i*8 + (t>>5);
    wS[k][t&31] = WiMt[(size_t)k*768 + r0 + (t&31)];
  }
  __syncthreads();
  int b = t>>3, rr = t&7;
  float a[4] = {0.f,0.f,0.f,0.f};
  for (int k=0;k<256;++k){
    float m = mS[b][k];
    #pragma unroll
    for (int u=0;u<4;++u) a[u] = fmaf(m, wS[k][rr + u*8], a[u]);
  }
  #pragma unroll
  for (int u=0;u<4;++u) gmsg[(size_t)b*768 + r0 + rr + u*8] = a[u];
}

// ---- GRU via MFMA + fused epilogue + s_next accumulation ----
// grid: (M/64) x 4 hcol-strips = 512 blocks. 4 waves as 2x2: wave = 32 rows x 32 cols per gate.
__global__ __launch_bounds__(256) void k_gru_mfma(
    const ushort_t* __restrict__ hbf_in,
    const ushort_t* __restrict__ WhB, const float* __restrict__ bh,
    const ushort_t* __restrict__ gjets, const float* __restrict__ gmsg,
    const float* __restrict__ w_edge,
    ushort_t* __restrict__ hbf_out, float* __restrict__ s_next, int compute_s)
{
  __shared__ __align__(16) short As[64*32];
  __shared__ __align__(16) short Bs[3*64*32];
  __shared__ float gm_s[192], bh_s[192];
  int t = threadIdx.x;
  int hcb = blockIdx.x & 3, mblk = blockIdx.x >> 2;
  int m0 = mblk*64, hc0 = hcb*64, b = m0 >> 8;
  if (t < 192){
    int g = t>>6, c = t&63;
    gm_s[t] = gmsg[b*768 + g*256 + hc0 + c];
    bh_s[t] = bh[g*256 + hc0 + c];
  }
  int lane = t & 63, w = t >> 6;
  int wr = w >> 1, wc = w & 1;
  int q = lane >> 4, r = lane & 15;
  int srow = t >> 2, sseg = t & 3;
  f32x4 acc[3][2][2] = {};
  for (int kt = 0; kt < 8; ++kt){
    __syncthreads();
    *(uint4*)&As[t*8] = *(const uint4*)&hbf_in[(size_t)(m0+srow)*256 + kt*32 + sseg*8];
    #pragma unroll
    for (int g = 0; g < 3; ++g)
      *(uint4*)&Bs[g*2048 + t*8] = *(const uint4*)&WhB[(size_t)(g*256 + hc0 + srow)*256 + kt*32 + sseg*8];
    __syncthreads();
    short8 af[2], bfr[3][2];
    #pragma unroll
    for (int fm=0; fm<2; ++fm)
      af[fm] = *(const short8*)&As[(wr*32 + fm*16 + r)*32 + q*8];
    #pragma unroll
    for (int g=0; g<3; ++g)
      #pragma unroll
      for (int fn=0; fn<2; ++fn)
        bfr[g][fn] = *(const short8*)&Bs[g*2048 + (wc*32 + fn*16 + r)*32 + q*8];
    #pragma unroll
    for (int g=0; g<3; ++g)
      #pragma unroll
      for (int fm=0; fm<2; ++fm)
        #pragma unroll
        for (int fn=0; fn<2; ++fn)
          acc[g][fm][fn] = __builtin_amdgcn_mfma_f32_16x16x32_bf16(af[fm], bfr[g][fn], acc[g][fm][fn], 0,0,0);
  }
  float wef[2];
  wef[0] = w_edge[hc0 + wc*32 + r];
  wef[1] = w_edge[hc0 + wc*32 + 16 + r];
  float pacc[2][4] = {};
  #pragma unroll
  for (int fm=0; fm<2; ++fm)
    #pragma unroll
    for (int fn=0; fn<2; ++fn){
      int cloc = wc*32 + fn*16 + r;
      int hcol = hc0 + cloc;
      #pragma unroll
      for (int jj=0; jj<4; ++jj){
        int m = m0 + wr*32 + fm*16 + q*4 + jj;
        float gir = bf2f(gjets[(size_t)m*768 + hcol])       + gm_s[cloc];
        float giz = bf2f(gjets[(size_t)m*768 + 256 + hcol]) + gm_s[64+cloc];
        float gin = bf2f(gjets[(size_t)m*768 + 512 + hcol]) + gm_s[128+cloc];
        float rr = sigmoidf_(gir + acc[0][fm][fn][jj] + bh_s[cloc]);
        float zz = sigmoidf_(giz + acc[1][fm][fn][jj] + bh_s[64+cloc]);
        float nn = tanhf(gin + rr*(acc[2][fm][fn][jj] + bh_s[128+cloc]));
        float ho = bf2f(hbf_in[(size_t)m*256 + hcol]);
        float hn = (1.f - zz)*nn + zz*ho;
        hbf_out[(size_t)m*256 + hcol] = f2bf(hn);
        pacc[fm][jj] = fmaf(wef[fn], hn, pacc[fm][jj]);
      }
    }
  if (compute_s){
    #pragma unroll
    for (int fm=0; fm<2; ++fm)
      #pragma unroll
      for (int jj=0; jj<4; ++jj){
        float p = pacc[fm][jj];
        p += __shfl_xor(p,1); p += __shfl_xor(p,2);
        p += __shfl_xor(p,4); p += __shfl_xor(p,8);
        if (r == 0)
          atomicAdd(&s_next[m0 + wr*32 + fm*16 + q*4 + jj], p);
      }
  }
}

// ---- readout via MFMA: y = relu(h@Wr1+br1), column-sum per batch -> zsum ----
__global__ __launch_bounds__(256) void k_readout_mfma(
    const ushort_t* __restrict__ hbf, const ushort_t* __restrict__ Wr1T,
    const float* __restrict__ br1, float* __restrict__ zsum)
{
  __shared__ __align__(16) short As[64*32];
  __shared__ __align__(16) short Bs[64*32];
  int t = threadIdx.x;
  int ncb = blockIdx.x & 3, mblk = blockIdx.x >> 2;
  int m0 = mblk*64, nc0 = ncb*64, b = m0 >> 8;
  int lane = t & 63, w = t >> 6;
  int wr = w >> 1, wc = w & 1;
  int q = lane >> 4, r = lane & 15;
  int srow = t >> 2, sseg = t & 3;
  f32x4 acc[2][2] = {};
  for (int kt = 0; kt < 8; ++kt){
    __syncthreads();
    *(uint4*)&As[t*8] = *(const uint4*)&hbf[(size_t)(m0+srow)*256 + kt*32 + sseg*8];
    *(uint4*)&Bs[t*8] = *(const uint4*)&Wr1T[(size_t)(nc0+srow)*256 + kt*32 + sseg*8];
    __syncthreads();
    short8 af[2], bfr[2];
    #pragma unroll
    for (int fm=0; fm<2; ++fm)
      af[fm] = *(const short8*)&As[(wr*32 + fm*16 + r)*32 + q*8];
    #pragma unroll
    for (int fn=0; fn<2; ++fn)
      bfr[fn] = *(const short8*)&Bs[(wc*32 + fn*16 + r)*32 + q*8];
    #pragma unroll
    for (int fm=0; fm<2; ++fm)
      #pragma unroll
      for (int fn=0; fn<2; ++fn)
        acc[fm][fn] = __builtin_amdgcn_mfma_f32_16x16x32_bf16(af[fm], bfr[fn], acc[fm][fn], 0,0,0);
  }
  #pragma unroll
  for (int fn=0; fn<2; ++fn){
    int n = nc0 + wc*32 + fn*16 + r;
    float bb = br1[n];
    float cs = 0.f;
    #pragma unroll
    for (int fm=0; fm<2; ++fm)
      #pragma unroll
      for (int jj=0; jj<4; ++jj)
        cs += fmaxf(acc[fm][fn][jj] + bb, 0.f);
    cs += __shfl_xor(cs, 16);
    cs += __shfl_xor(cs, 32);
    if (q == 0) atomicAdd(&zsum[b*256 + n], cs);
  }
}

// ---- final: out[b,:] = zsum[b,:]@Wr2 + N*br2 ----
__global__ __launch_bounds__(256) void k_final(const float* __restrict__ zsum,
    const float* __restrict__ Wr2, const float* __restrict__ br2,
    float* __restrict__ out){
  int b = blockIdx.x, t = threadIdx.x;
  __shared__ float zs[NH];
  zs[t] = zsum[b*NH + t];
  __syncthreads();
  float acc = 0.f;
  for (int k=0;k<NH;++k) acc = fmaf(zs[k], Wr2[k*NH + t], acc);
  out[b*NH + t] = acc + 256.0f*br2[t];
}

extern "C" void kernel_launch(void* const* d_in, const int* in_sizes, int n_in,
                              void* d_out, int out_size, void* d_ws, size_t ws_size,
                              hipStream_t stream){
  (void)in_sizes; (void)n_in; (void)out_size; (void)ws_size;
  const float* jets  = (const float*)d_in[0];
  const float* W_emb = (const float*)d_in[1];
  const float* b_emb = (const float*)d_in[2];
  const float* w_edge= (const float*)d_in[3];
  // d_in[4] = b_edge: cancels in softmax
  const float* W_msg = (const float*)d_in[5];
  const float* b_msg = (const float*)d_in[6];
  const float* Wi    = (const float*)d_in[7];
  const float* bi    = (const float*)d_in[8];
  const float* Wh    = (const float*)d_in[9];
  const float* bh    = (const float*)d_in[10];
  const float* Wr1   = (const float*)d_in[11];
  const float* br1   = (const float*)d_in[12];
  const float* Wr2   = (const float*)d_in[13];
  const float* br2   = (const float*)d_in[14];
  float* out = (float*)d_out;
  float* ws = (float*)d_ws;
  // workspace (float-slot units)
  ushort_t* hbf_0 = (ushort_t*)(ws);               // 1,048,576 f
  ushort_t* hbf_1 = (ushort_t*)(ws + 1048576);     // 1,048,576 f
  ushort_t* gjets = (ushort_t*)(ws + 2097152);     // 3,145,728 f
  float* gmsg  = ws + 5242880;                     // 24,576
  float* zsum  = ws + 5267456;                     // 8,192
  float* WiJt  = ws + 5275648;                     // 6,144
  float* WiMt  = ws + 5281792;                     // 196,608
  ushort_t* WhB  = (ushort_t*)(ws + 5478400);      // 98,304 f
  ushort_t* Wr1T = (ushort_t*)(ws + 5576704);      // 32,768 f
  float* s_buf0 = ws + 5609472;                    // 8,192
  float* s_buf1 = ws + 5617664;                    // 8,192
  float* hbar   = ws + 5625856;                    // 8,192
  float* mv     = ws + 5634048;                    // 8,192  (end 5,642,240 f = 22.6MB)
  ushort_t* hbf[2] = {hbf_0, hbf_1};
  float* s_bufs[2] = {s_buf0, s_buf1};

  hipMemsetAsync(zsum, 0, NB*NH*sizeof(float), stream);
  k_prep<<<256,256,0,stream>>>(Wi, Wh, Wr1, WiJt, WiMt, WhB, Wr1T);
  k_embed<<<NB*NN,256,0,stream>>>(jets, W_emb, b_emb, bi, WiJt, w_edge,
                                  hbf[0], gjets, s_bufs[0]);
  for (int it=0; it<NITERS; ++it){
    int cur = it & 1, nxt = cur ^ 1;
    hipMemsetAsync(hbar, 0, NB*NH*sizeof(float), stream);
    k_attn_hbar<<<NB*8,256,0,stream>>>(hbf[cur], s_bufs[cur], hbar);
    k_msg<<<16,256,0,stream>>>(hbar, W_msg, b_msg, mv);
    k_gmsg<<<24,256,0,stream>>>(mv, WiMt, gmsg);
    int compute_s = (it < NITERS-1) ? 1 : 0;
    if (compute_s)
      hipMemsetAsync(s_bufs[nxt], 0, NB*NN*sizeof(float), stream);
    k_gru_mfma<<<512,256,0,stream>>>(hbf[cur], WhB, bh, gjets, gmsg, w_edge,
                                     hbf[nxt], s_bufs[nxt], compute_s);
  }
  k_readout_mfma<<<512,256,0,stream>>>(hbf[NITERS&1], Wr1T, br1, zsum);
  k_final<<<NB,256,0,stream>>>(zsum, Wr2, br2, out);
}